// Round 1
// baseline (1333.756 us; speedup 1.0000x reference)
//
#include <hip/hip_runtime.h>
#include <math.h>

#define N_BOX 8192
#define NW 128              // 8192 / 64 words per row
#define THR_C 0.7f
#define IOU_THR_C 0.5f
#define EPS_C 1e-9f

// SCALER = max(3508/1280, 2480/1280) computed in double then rounded to f32,
// matching numpy/jax float32 weak-typed scalar promotion.
__device__ __constant__ float kScaler = (float)(3508.0 / 1280.0);

static __device__ inline unsigned long long shfl64(unsigned long long v, int src) {
    int lo = __shfl((int)(v & 0xffffffffull), src, 64);
    int hi = __shfl((int)(v >> 32), src, 64);
    return ((unsigned long long)(unsigned int)hi << 32) | (unsigned int)lo;
}

// ---------------------------------------------------------------------------
// Kernel 1: build 64-bit sort keys and bitonic-sort them in LDS (one block).
// key = (~monotonic(masked_score) << 32) | idx  -> ascending sort == stable
// descending argsort of masked scores with index-ascending tie-break.
// ---------------------------------------------------------------------------
__global__ __launch_bounds__(1024) void sort_kernel(const float* __restrict__ cls_conf,
                                                    unsigned long long* __restrict__ keys) {
    __shared__ unsigned long long s[N_BOX];   // 64 KiB
    for (int i = threadIdx.x; i < N_BOX; i += 1024) {
        float c0 = cls_conf[2 * i], c1 = cls_conf[2 * i + 1];
        bool valid = (c0 > THR_C) || (c1 > THR_C);
        float score = fmaxf(c0, c1);
        float ms = valid ? score : -INFINITY;
        unsigned int u = __float_as_uint(ms);
        unsigned int m = (u & 0x80000000u) ? ~u : (u | 0x80000000u); // ascending map
        unsigned int d = ~m;                                         // descending key
        s[i] = ((unsigned long long)d << 32) | (unsigned int)i;
    }
    __syncthreads();
    for (int k = 2; k <= N_BOX; k <<= 1) {
        for (int j = k >> 1; j > 0; j >>= 1) {
            for (int t = threadIdx.x; t < N_BOX / 2; t += 1024) {
                int i = ((t & ~(j - 1)) << 1) | (t & (j - 1));
                int p = i | j;
                bool up = ((i & k) == 0);
                unsigned long long a = s[i], b = s[p];
                bool swap = up ? (a > b) : (a < b);
                if (swap) { s[i] = b; s[p] = a; }
            }
            __syncthreads();
        }
    }
    for (int i = threadIdx.x; i < N_BOX; i += 1024) keys[i] = s[i];
}

// ---------------------------------------------------------------------------
// Kernel 2: gather sorted boxes / order / valid flags.
// ---------------------------------------------------------------------------
__global__ void gather_kernel(const unsigned long long* __restrict__ keys,
                              const float* __restrict__ bboxes,
                              const float* __restrict__ conf,
                              float4* __restrict__ sb,
                              unsigned int* __restrict__ order,
                              unsigned char* __restrict__ validb) {
    int i = blockIdx.x * 256 + threadIdx.x;
    unsigned long long k = keys[i];
    unsigned int o = (unsigned int)(k & 0xffffffffull);
    order[i] = o;
    sb[i] = ((const float4*)bboxes)[o];
    float c0 = conf[2 * o], c1 = conf[2 * o + 1];
    validb[i] = ((c0 > THR_C) || (c1 > THR_C)) ? 1 : 0;
}

// ---------------------------------------------------------------------------
// Kernel 3: suppression bit-matrix. mask[i][w] bit b = (iou(i, 64w+b) > thr
// && 64w+b > i). Exact IEEE fp32 division to match the reference rounding.
// grid: (32, 128), block 256.
// ---------------------------------------------------------------------------
__global__ void mask_kernel(const float4* __restrict__ sb,
                            unsigned long long* __restrict__ mask) {
    __shared__ float4 cb[64];
    __shared__ float carea[64];
    int w = blockIdx.y;
    if (threadIdx.x < 64) {
        float4 c = sb[(w << 6) + threadIdx.x];
        cb[threadIdx.x] = c;
        carea[threadIdx.x] = (c.z - c.x) * (c.w - c.y);
    }
    __syncthreads();
    int i = blockIdx.x * 256 + threadIdx.x;
    float4 r = sb[i];
    float ra = (r.z - r.x) * (r.w - r.y);
    unsigned long long bits = 0ull;
    int jbase = w << 6;
#pragma unroll 8
    for (int b = 0; b < 64; ++b) {
        float4 c = cb[b];
        float iw = fminf(r.z, c.z) - fmaxf(r.x, c.x);
        float ih = fminf(r.w, c.w) - fmaxf(r.y, c.y);
        iw = fmaxf(iw, 0.0f);
        ih = fmaxf(ih, 0.0f);
        float inter = iw * ih;
        float iou = inter / (ra + carea[b] - inter + EPS_C);
        if ((iou > IOU_THR_C) && ((jbase + b) > i)) bits |= (1ull << b);
    }
    mask[(size_t)i * NW + w] = bits;
}

// ---------------------------------------------------------------------------
// Kernel 4: sequential greedy scan, one wave. Lane l owns removal words l and
// l+64. The current decision word `cur` is replicated in every lane and
// refreshed via the (broadcast) load of mask[i][w], so the loop-carried chain
// is a bit-test + predicated ORs only.
// ---------------------------------------------------------------------------
__global__ __launch_bounds__(64) void scan_kernel(const unsigned long long* __restrict__ mask,
                                                  const unsigned char* __restrict__ validb,
                                                  unsigned long long* __restrict__ keepw) {
    int lane = threadIdx.x;
    unsigned long long r0 = 0ull, r1 = 0ull;
    // init: removed = !valid
    for (int w = 0; w < NW; ++w) {
        unsigned long long bw = ~__ballot(validb[(w << 6) + lane] != 0);
        if (w == lane) r0 = bw;
        if (w == lane + 64) r1 = bw;
    }
    for (int w = 0; w < NW; ++w) {
        unsigned long long cur = (w < 64) ? shfl64(r0, w) : shfl64(r1, w - 64);
        const unsigned long long* rowp = mask + ((size_t)(w << 6) * NW);
#pragma unroll 8
        for (int b = 0; b < 64; ++b) {
            unsigned long long m0 = rowp[lane];
            unsigned long long m1 = rowp[64 + lane];
            unsigned long long mw = rowp[w];
            bool kept = !((cur >> b) & 1ull);
            if (kept) {
                r0 |= m0;
                r1 |= m1;
                cur |= mw;
            }
            rowp += NW;
        }
    }
    keepw[lane] = r0;
    keepw[64 + lane] = r1;
}

// ---------------------------------------------------------------------------
// Kernel 5: write (N,6) output: [boxes*SCALER*kf, conf*kf]
// ---------------------------------------------------------------------------
__global__ void out_kernel(const float4* __restrict__ sb,
                           const unsigned long long* __restrict__ keepw,
                           const unsigned int* __restrict__ order,
                           const float* __restrict__ conf,
                           float* __restrict__ out) {
    int i = blockIdx.x * 256 + threadIdx.x;
    float kf = ((keepw[i >> 6] >> (i & 63)) & 1ull) ? 0.0f : 1.0f;
    float4 b = sb[i];
    unsigned int o = order[i];
    float s = kScaler * kf;
    out[i * 6 + 0] = b.x * s;
    out[i * 6 + 1] = b.y * s;
    out[i * 6 + 2] = b.z * s;
    out[i * 6 + 3] = b.w * s;
    out[i * 6 + 4] = conf[2 * o] * kf;
    out[i * 6 + 5] = conf[2 * o + 1] * kf;
}

extern "C" void kernel_launch(void* const* d_in, const int* in_sizes, int n_in,
                              void* d_out, int out_size, void* d_ws, size_t ws_size,
                              hipStream_t stream) {
    const float* cls_conf = (const float*)d_in[0];   // (8192, 2)
    const float* bboxes   = (const float*)d_in[1];   // (8192, 4)
    float* out = (float*)d_out;                      // (8192, 6)

    char* ws = (char*)d_ws;
    unsigned long long* keys  = (unsigned long long*)(ws + 0);        //  64 KiB
    float4*             sb    = (float4*)(ws + 65536);                // 128 KiB
    unsigned int*       order = (unsigned int*)(ws + 196608);         //  32 KiB
    unsigned char*      valb  = (unsigned char*)(ws + 229376);        //   8 KiB
    unsigned long long* mask  = (unsigned long long*)(ws + 237568);   //   8 MiB
    unsigned long long* keepw = (unsigned long long*)(ws + 8626176);  //   1 KiB

    sort_kernel<<<1, 1024, 0, stream>>>(cls_conf, keys);
    gather_kernel<<<N_BOX / 256, 256, 0, stream>>>(keys, bboxes, cls_conf, sb, order, valb);
    mask_kernel<<<dim3(32, 128), 256, 0, stream>>>(sb, mask);
    scan_kernel<<<1, 64, 0, stream>>>(mask, valb, keepw);
    out_kernel<<<N_BOX / 256, 256, 0, stream>>>(sb, keepw, order, cls_conf, out);
}

// Round 2
// 773.695 us; speedup vs baseline: 1.7239x; 1.7239x over previous
//
#include <hip/hip_runtime.h>
#include <math.h>

#define N_BOX 8192
#define NW 128              // 8192 / 64 words per row
#define THR_C 0.7f
#define IOU_THR_C 0.5f
#define EPS_C 1e-9f

// SCALER = max(3508/1280, 2480/1280) computed in double then rounded to f32,
// matching numpy/jax float32 weak-typed scalar promotion.
__device__ __constant__ float kScaler = (float)(3508.0 / 1280.0);

static __device__ inline unsigned long long shfl64(unsigned long long v, int src) {
    int lo = __shfl((int)(v & 0xffffffffull), src, 64);
    int hi = __shfl((int)(v >> 32), src, 64);
    return ((unsigned long long)(unsigned int)hi << 32) | (unsigned int)lo;
}

// ---------------------------------------------------------------------------
// Kernel 1: build 64-bit sort keys and bitonic-sort them in LDS (one block).
// key = (~monotonic(masked_score) << 32) | idx  -> ascending sort == stable
// descending argsort of masked scores with index-ascending tie-break.
// ---------------------------------------------------------------------------
__global__ __launch_bounds__(1024) void sort_kernel(const float* __restrict__ cls_conf,
                                                    unsigned long long* __restrict__ keys) {
    __shared__ unsigned long long s[N_BOX];   // 64 KiB
    for (int i = threadIdx.x; i < N_BOX; i += 1024) {
        float c0 = cls_conf[2 * i], c1 = cls_conf[2 * i + 1];
        bool valid = (c0 > THR_C) || (c1 > THR_C);
        float score = fmaxf(c0, c1);
        float ms = valid ? score : -INFINITY;
        unsigned int u = __float_as_uint(ms);
        unsigned int m = (u & 0x80000000u) ? ~u : (u | 0x80000000u); // ascending map
        unsigned int d = ~m;                                         // descending key
        s[i] = ((unsigned long long)d << 32) | (unsigned int)i;
    }
    __syncthreads();
    for (int k = 2; k <= N_BOX; k <<= 1) {
        for (int j = k >> 1; j > 0; j >>= 1) {
            for (int t = threadIdx.x; t < N_BOX / 2; t += 1024) {
                int i = ((t & ~(j - 1)) << 1) | (t & (j - 1));
                int p = i | j;
                bool up = ((i & k) == 0);
                unsigned long long a = s[i], b = s[p];
                bool swap = up ? (a > b) : (a < b);
                if (swap) { s[i] = b; s[p] = a; }
            }
            __syncthreads();
        }
    }
    for (int i = threadIdx.x; i < N_BOX; i += 1024) keys[i] = s[i];
}

// ---------------------------------------------------------------------------
// Kernel 2: gather sorted boxes / order / valid flags.
// ---------------------------------------------------------------------------
__global__ void gather_kernel(const unsigned long long* __restrict__ keys,
                              const float* __restrict__ bboxes,
                              const float* __restrict__ conf,
                              float4* __restrict__ sb,
                              unsigned int* __restrict__ order,
                              unsigned char* __restrict__ validb) {
    int i = blockIdx.x * 256 + threadIdx.x;
    unsigned long long k = keys[i];
    unsigned int o = (unsigned int)(k & 0xffffffffull);
    order[i] = o;
    sb[i] = ((const float4*)bboxes)[o];
    float c0 = conf[2 * o], c1 = conf[2 * o + 1];
    validb[i] = ((c0 > THR_C) || (c1 > THR_C)) ? 1 : 0;
}

// ---------------------------------------------------------------------------
// Kernel 3: suppression bit-matrix. mask[i][w] bit b = (iou(i, 64w+b) > thr
// && 64w+b > i). Exact IEEE fp32 division to match the reference rounding.
// grid: (32, 128), block 256.
// ---------------------------------------------------------------------------
__global__ void mask_kernel(const float4* __restrict__ sb,
                            unsigned long long* __restrict__ mask) {
    __shared__ float4 cb[64];
    __shared__ float carea[64];
    int w = blockIdx.y;
    if (threadIdx.x < 64) {
        float4 c = sb[(w << 6) + threadIdx.x];
        cb[threadIdx.x] = c;
        carea[threadIdx.x] = (c.z - c.x) * (c.w - c.y);
    }
    __syncthreads();
    int i = blockIdx.x * 256 + threadIdx.x;
    float4 r = sb[i];
    float ra = (r.z - r.x) * (r.w - r.y);
    unsigned long long bits = 0ull;
    int jbase = w << 6;
#pragma unroll 8
    for (int b = 0; b < 64; ++b) {
        float4 c = cb[b];
        float iw = fminf(r.z, c.z) - fmaxf(r.x, c.x);
        float ih = fminf(r.w, c.w) - fmaxf(r.y, c.y);
        iw = fmaxf(iw, 0.0f);
        ih = fmaxf(ih, 0.0f);
        float inter = iw * ih;
        float iou = inter / (ra + carea[b] - inter + EPS_C);
        if ((iou > IOU_THR_C) && ((jbase + b) > i)) bits |= (1ull << b);
    }
    mask[(size_t)i * NW + w] = bits;
}

// ---------------------------------------------------------------------------
// Kernel 4: block-parallel greedy scan. One block, 16 waves.
// 128 groups of 64 rows. Per group:
//   step B (wave 0): serial 64-bit scan over the diagonal 64x64 mask block,
//     using shfl64 broadcasts of per-lane diag words (shfl inputs are
//     independent of the carried `cur`, so the serial chain is test+or only).
//   step C (all waves): OR kept rows' mask words into the LDS removal bitset
//     for words > w (words <= w are structurally zero / never read again).
//     Wave-uniform kept-bit predication skips ~half the rows.
// ---------------------------------------------------------------------------
__global__ __launch_bounds__(1024) void scan_kernel(const unsigned long long* __restrict__ mask,
                                                    const unsigned char* __restrict__ validb,
                                                    unsigned long long* __restrict__ keepw) {
    __shared__ unsigned long long rem[NW];   // removal bitset, 1 KiB
    __shared__ unsigned long long kwS;       // current group's kept-row word
    int t = threadIdx.x;
    int lane = t & 63;
    int wv = t >> 6;                         // wave id 0..15
    // init: rem[w] = ~valid ballot
    for (int w = wv; w < NW; w += 16) {
        unsigned long long bw = ~__ballot(validb[(w << 6) + lane] != 0);
        if (lane == 0) rem[w] = bw;
    }
    __syncthreads();
    int sub = t >> 7;                        // 0..7 (uniform within a wave)
    int wd  = t & 127;
    for (int w = 0; w < NW; ++w) {
        if (t < 64) {
            // diag word of row (64w+lane): mask[64w+lane][w]
            unsigned long long dl = mask[(size_t)((w << 6) + lane) * NW + w];
            unsigned long long cur = rem[w];
#pragma unroll
            for (int b = 0; b < 64; ++b) {
                unsigned long long tk = shfl64(dl, b);
                if (!((cur >> b) & 1ull)) cur |= tk;
            }
            if (lane == 0) { kwS = ~cur; keepw[w] = cur; }
        }
        __syncthreads();
        unsigned long long kw = kwS;
        // step C: apply kept rows of group w to later words
        if (wd > w && kw) {
            const unsigned long long* rp = mask + (size_t)(w << 6) * NW + wd;
            unsigned long long acc = 0ull;
#pragma unroll
            for (int k = 0; k < 8; ++k) {
                int rr = (sub << 3) + k;     // wave-uniform row index
                if ((kw >> rr) & 1ull) acc |= rp[(size_t)rr * NW];
            }
            if (acc) atomicOr(&rem[wd], acc);
        }
        __syncthreads();
    }
}

// ---------------------------------------------------------------------------
// Kernel 5: write (N,6) output: [boxes*SCALER*kf, conf*kf]
// ---------------------------------------------------------------------------
__global__ void out_kernel(const float4* __restrict__ sb,
                           const unsigned long long* __restrict__ keepw,
                           const unsigned int* __restrict__ order,
                           const float* __restrict__ conf,
                           float* __restrict__ out) {
    int i = blockIdx.x * 256 + threadIdx.x;
    float kf = ((keepw[i >> 6] >> (i & 63)) & 1ull) ? 0.0f : 1.0f;
    float4 b = sb[i];
    unsigned int o = order[i];
    float s = kScaler * kf;
    out[i * 6 + 0] = b.x * s;
    out[i * 6 + 1] = b.y * s;
    out[i * 6 + 2] = b.z * s;
    out[i * 6 + 3] = b.w * s;
    out[i * 6 + 4] = conf[2 * o] * kf;
    out[i * 6 + 5] = conf[2 * o + 1] * kf;
}

extern "C" void kernel_launch(void* const* d_in, const int* in_sizes, int n_in,
                              void* d_out, int out_size, void* d_ws, size_t ws_size,
                              hipStream_t stream) {
    const float* cls_conf = (const float*)d_in[0];   // (8192, 2)
    const float* bboxes   = (const float*)d_in[1];   // (8192, 4)
    float* out = (float*)d_out;                      // (8192, 6)

    char* ws = (char*)d_ws;
    unsigned long long* keys  = (unsigned long long*)(ws + 0);        //  64 KiB
    float4*             sb    = (float4*)(ws + 65536);                // 128 KiB
    unsigned int*       order = (unsigned int*)(ws + 196608);         //  32 KiB
    unsigned char*      valb  = (unsigned char*)(ws + 229376);        //   8 KiB
    unsigned long long* mask  = (unsigned long long*)(ws + 237568);   //   8 MiB
    unsigned long long* keepw = (unsigned long long*)(ws + 8626176);  //   1 KiB

    sort_kernel<<<1, 1024, 0, stream>>>(cls_conf, keys);
    gather_kernel<<<N_BOX / 256, 256, 0, stream>>>(keys, bboxes, cls_conf, sb, order, valb);
    mask_kernel<<<dim3(32, 128), 256, 0, stream>>>(sb, mask);
    scan_kernel<<<1, 1024, 0, stream>>>(mask, valb, keepw);
    out_kernel<<<N_BOX / 256, 256, 0, stream>>>(sb, keepw, order, cls_conf, out);
}

// Round 3
// 306.229 us; speedup vs baseline: 4.3554x; 2.5265x over previous
//
#include <hip/hip_runtime.h>
#include <math.h>

#define N_BOX 8192
#define NW 128              // 8192 / 64 words per row
#define THR_C 0.7f
#define IOU_THR_C 0.5f
#define EPS_C 1e-9f

// SCALER = max(3508/1280, 2480/1280) computed in double then rounded to f32,
// matching numpy/jax float32 weak-typed scalar promotion.
__device__ __constant__ float kScaler = (float)(3508.0 / 1280.0);

// ---------------------------------------------------------------------------
// Kernel 1: build 64-bit sort keys and bitonic-sort them in LDS (one block).
// key = (~monotonic(masked_score) << 32) | idx  -> ascending sort == stable
// descending argsort of masked scores with index-ascending tie-break.
// ---------------------------------------------------------------------------
__global__ __launch_bounds__(1024) void sort_kernel(const float* __restrict__ cls_conf,
                                                    unsigned long long* __restrict__ keys) {
    __shared__ unsigned long long s[N_BOX];   // 64 KiB
    for (int i = threadIdx.x; i < N_BOX; i += 1024) {
        float c0 = cls_conf[2 * i], c1 = cls_conf[2 * i + 1];
        bool valid = (c0 > THR_C) || (c1 > THR_C);
        float score = fmaxf(c0, c1);
        float ms = valid ? score : -INFINITY;
        unsigned int u = __float_as_uint(ms);
        unsigned int m = (u & 0x80000000u) ? ~u : (u | 0x80000000u); // ascending map
        unsigned int d = ~m;                                         // descending key
        s[i] = ((unsigned long long)d << 32) | (unsigned int)i;
    }
    __syncthreads();
    for (int k = 2; k <= N_BOX; k <<= 1) {
        for (int j = k >> 1; j > 0; j >>= 1) {
            for (int t = threadIdx.x; t < N_BOX / 2; t += 1024) {
                int i = ((t & ~(j - 1)) << 1) | (t & (j - 1));
                int p = i | j;
                bool up = ((i & k) == 0);
                unsigned long long a = s[i], b = s[p];
                bool swap = up ? (a > b) : (a < b);
                if (swap) { s[i] = b; s[p] = a; }
            }
            __syncthreads();
        }
    }
    for (int i = threadIdx.x; i < N_BOX; i += 1024) keys[i] = s[i];
}

// ---------------------------------------------------------------------------
// Kernel 2: gather sorted boxes / order / valid word bitmaps (per-wave ballot).
// Block 0 also zero-inits nzoffG (ws is poisoned 0xAA; mask_kernel atomicOrs
// into it and runs after us on the same stream).
// ---------------------------------------------------------------------------
__global__ void gather_kernel(const unsigned long long* __restrict__ keys,
                              const float* __restrict__ bboxes,
                              const float* __restrict__ conf,
                              float4* __restrict__ sb,
                              unsigned int* __restrict__ order,
                              unsigned long long* __restrict__ validw,
                              unsigned long long* __restrict__ nzoffG) {
    int i = blockIdx.x * 256 + threadIdx.x;
    if (blockIdx.x == 0 && threadIdx.x < NW) nzoffG[threadIdx.x] = 0ull;
    unsigned long long k = keys[i];
    unsigned int o = (unsigned int)(k & 0xffffffffull);
    order[i] = o;
    sb[i] = ((const float4*)bboxes)[o];
    float c0 = conf[2 * o], c1 = conf[2 * o + 1];
    unsigned long long vb = __ballot((c0 > THR_C) || (c1 > THR_C));
    if ((threadIdx.x & 63) == 0) validw[i >> 6] = vb;
}

// ---------------------------------------------------------------------------
// Kernel 3: suppression bit-matrix + sparsity metadata.
//   mask[i][w] bit b = (iou(i, 64w+b) > thr && 64w+b > i)
//   diagG[i]  = mask[i][i>>6]          (compact copy of the diagonal block)
//   dnzG[w]   bit r = (diag word of row 64w+r) != 0
//   nzoffG[w] bit r = row 64w+r has some nonzero OFF-diagonal word
// Exact IEEE fp32 division to match the reference rounding. grid (32,128)x256.
// ---------------------------------------------------------------------------
__global__ void mask_kernel(const float4* __restrict__ sb,
                            unsigned long long* __restrict__ mask,
                            unsigned long long* __restrict__ diagG,
                            unsigned long long* __restrict__ dnzG,
                            unsigned long long* __restrict__ nzoffG) {
    __shared__ float4 cb[64];
    __shared__ float carea[64];
    int w = blockIdx.y;
    if (threadIdx.x < 64) {
        float4 c = sb[(w << 6) + threadIdx.x];
        cb[threadIdx.x] = c;
        carea[threadIdx.x] = (c.z - c.x) * (c.w - c.y);
    }
    __syncthreads();
    int i = blockIdx.x * 256 + threadIdx.x;
    float4 r = sb[i];
    float ra = (r.z - r.x) * (r.w - r.y);
    unsigned long long bits = 0ull;
    int jbase = w << 6;
#pragma unroll 8
    for (int b = 0; b < 64; ++b) {
        float4 c = cb[b];
        float iw = fminf(r.z, c.z) - fmaxf(r.x, c.x);
        float ih = fminf(r.w, c.w) - fmaxf(r.y, c.y);
        iw = fmaxf(iw, 0.0f);
        ih = fmaxf(ih, 0.0f);
        float inter = iw * ih;
        float iou = inter / (ra + carea[b] - inter + EPS_C);
        if ((iou > IOU_THR_C) && ((jbase + b) > i)) bits |= (1ull << b);
    }
    mask[(size_t)i * NW + w] = bits;
    // wave-uniform: i>>6 constant across a wave, w uniform
    unsigned long long bb = __ballot(bits != 0ull);
    if ((i >> 6) == w) {
        diagG[i] = bits;
        if ((i & 63) == 0) dnzG[w] = bb;
    } else {
        if (bb && ((i & 63) == 0)) atomicOr(&nzoffG[i >> 6], bb);
    }
}

// ---------------------------------------------------------------------------
// Kernel 4: block-parallel greedy scan, 256 threads (4 waves), sparse.
// All diag words preloaded to LDS (64 KiB). Per group w:
//   step B (wave 0): cur = rem[w]; serial scan only over dnz-set rows via
//     ctz, reading diag words from LDS (no shfl / no bpermute chain).
//   step C: thread t owns word wd = t&127, row-half (t>>7); iterates
//     kept&nzoff rows via ctz with 4-batched independent loads (duplicates
//     idempotent under OR) so L2 latency is amortized; LDS atomicOr into rem.
// ---------------------------------------------------------------------------
__global__ __launch_bounds__(256) void scan_kernel(const unsigned long long* __restrict__ mask,
                                                   const unsigned long long* __restrict__ validw,
                                                   const unsigned long long* __restrict__ diagG,
                                                   const unsigned long long* __restrict__ dnzG,
                                                   const unsigned long long* __restrict__ nzoffG,
                                                   unsigned long long* __restrict__ keepw) {
    __shared__ unsigned long long diagL[N_BOX];   // 64 KiB
    __shared__ unsigned long long remL[NW];
    __shared__ unsigned long long dnzL[NW];
    __shared__ unsigned long long nzoffL[NW];
    __shared__ unsigned long long kwS;
    int t = threadIdx.x;
    for (int i = t; i < N_BOX; i += 256) diagL[i] = diagG[i];
    for (int w = t; w < NW; w += 256) {
        remL[w] = ~validw[w];
        dnzL[w] = dnzG[w];
        nzoffL[w] = nzoffG[w];
    }
    __syncthreads();
    int wd = t & 127;
    int half = t >> 7;                    // 0 or 1: rows [0,32) or [32,64)
    for (int w = 0; w < NW; ++w) {
        if (t < 64) {
            unsigned long long cur = remL[w];
            unsigned long long dn = dnzL[w];
            while (dn) {
                int r = __builtin_ctzll(dn);
                dn &= dn - 1;
                if (!((cur >> r) & 1ull)) cur |= diagL[(w << 6) + r];
            }
            if (t == 0) { keepw[w] = cur; kwS = ~cur & nzoffL[w]; }
        }
        __syncthreads();
        if (wd > w) {
            unsigned long long kw = (kwS >> (half << 5)) & 0xffffffffull;
            if (kw) {
                const unsigned long long* rp =
                    mask + (size_t)((w << 6) + (half << 5)) * NW + wd;
                unsigned long long acc = 0ull;
                while (kw) {
                    int r0 = __builtin_ctzll(kw); kw &= kw - 1;
                    int r1 = r0, r2 = r0, r3 = r0;
                    if (kw) { r1 = __builtin_ctzll(kw); kw &= kw - 1; }
                    if (kw) { r2 = __builtin_ctzll(kw); kw &= kw - 1; }
                    if (kw) { r3 = __builtin_ctzll(kw); kw &= kw - 1; }
                    acc |= rp[(size_t)r0 * NW] | rp[(size_t)r1 * NW]
                         | rp[(size_t)r2 * NW] | rp[(size_t)r3 * NW];
                }
                if (acc) atomicOr(&remL[wd], acc);
            }
        }
        __syncthreads();
    }
}

// ---------------------------------------------------------------------------
// Kernel 5: write (N,6) output: [boxes*SCALER*kf, conf*kf]
// ---------------------------------------------------------------------------
__global__ void out_kernel(const float4* __restrict__ sb,
                           const unsigned long long* __restrict__ keepw,
                           const unsigned int* __restrict__ order,
                           const float* __restrict__ conf,
                           float* __restrict__ out) {
    int i = blockIdx.x * 256 + threadIdx.x;
    float kf = ((keepw[i >> 6] >> (i & 63)) & 1ull) ? 0.0f : 1.0f;
    float4 b = sb[i];
    unsigned int o = order[i];
    float s = kScaler * kf;
    out[i * 6 + 0] = b.x * s;
    out[i * 6 + 1] = b.y * s;
    out[i * 6 + 2] = b.z * s;
    out[i * 6 + 3] = b.w * s;
    out[i * 6 + 4] = conf[2 * o] * kf;
    out[i * 6 + 5] = conf[2 * o + 1] * kf;
}

extern "C" void kernel_launch(void* const* d_in, const int* in_sizes, int n_in,
                              void* d_out, int out_size, void* d_ws, size_t ws_size,
                              hipStream_t stream) {
    const float* cls_conf = (const float*)d_in[0];   // (8192, 2)
    const float* bboxes   = (const float*)d_in[1];   // (8192, 4)
    float* out = (float*)d_out;                      // (8192, 6)

    char* ws = (char*)d_ws;
    unsigned long long* keys   = (unsigned long long*)(ws + 0);        //  64 KiB
    float4*             sb     = (float4*)(ws + 65536);                // 128 KiB
    unsigned int*       order  = (unsigned int*)(ws + 196608);         //  32 KiB
    unsigned long long* validw = (unsigned long long*)(ws + 229376);   //   1 KiB
    unsigned long long* mask   = (unsigned long long*)(ws + 237568);   //   8 MiB
    unsigned long long* keepw  = (unsigned long long*)(ws + 8626176);  //   1 KiB
    unsigned long long* diagG  = (unsigned long long*)(ws + 8627200);  //  64 KiB
    unsigned long long* dnzG   = (unsigned long long*)(ws + 8692736);  //   1 KiB
    unsigned long long* nzoffG = (unsigned long long*)(ws + 8693760);  //   1 KiB

    sort_kernel<<<1, 1024, 0, stream>>>(cls_conf, keys);
    gather_kernel<<<N_BOX / 256, 256, 0, stream>>>(keys, bboxes, cls_conf, sb, order,
                                                   validw, nzoffG);
    mask_kernel<<<dim3(32, 128), 256, 0, stream>>>(sb, mask, diagG, dnzG, nzoffG);
    scan_kernel<<<1, 256, 0, stream>>>(mask, validw, diagG, dnzG, nzoffG, keepw);
    out_kernel<<<N_BOX / 256, 256, 0, stream>>>(sb, keepw, order, cls_conf, out);
}